// Round 9
// baseline (2512.803 us; speedup 1.0000x reference)
//
#include <hip/hip_runtime.h>
#include <math.h>

// Per-sample fully-fused iterated CNN. Persistent blocks, 256 threads, atomic
// work-stealing, 3 blocks/CU, FULL fp32 (rounds 3/4: any mantissa compression
// is chaotically amplified ~10x/iter -> fails). VGPR pinned by COUNT
// (amdgpu_num_vgpr; wave-based hints are broken: launch_bounds(256,3)->84,
// waves_per_eu(4)->64, both spilled catastrophically).
// ROUND-9 DIAGNOSIS: kernel is LDS-PIPE-bound (one pipe/CU, no SIMD
// parallelism): conv2 did 1456 ds_read_b32/thread (H1W=31 odd -> scalar) =
// ~530us of pipe time; explains 3->4 blocks flat, prefetch flat, stagger flat.
// FIX (this round): (1) c-PAIRING -- threads with same spatial window but
// different c read identical h1 data; each thread now computes 2 channels per
// row load (240 thr = 8 cpair x 15 spatial x 2 h). (2) H1W=34 (even) -> b64
// row reads (7 vs 13 insts). (3) fc reads pbuf as float4; conv1 writes float2.
// conv2 LDS insts/thread: 1456 -> 392.
#define RP40S 44   // (-1)-padded 40x44 state (16B-aligned rows)
#define H1W   34   // h1 col stride: EVEN (b64 rows); 2 left pads + 28 + 4 right
                   // pad cols (zeros). 6-row pyg stride=204=12 mod 32, c-plane
                   // 952=24 mod 32 -> conv2 lane addrs spread across banks.

struct SharedBufs {
    float rp40[40*RP40S];   //  7040 B  (state, -1 pads, persists)
    float h1p[8*28*H1W];    // 30464 B  (conv1 activations, fp32, zero col-pads)
    float pbuf[1296];       //  5184 B  (pooled feats -> fc input, 16B-aligned)
    float wker[169];        //   676 B
    float num_s[10];        //    40 B
    int   next;             //     4 B  (work-stealing broadcast slot)
};                          // 43408 B -> 3 blocks/CU (160KB/3 = 54.6KB cap)

template<int OUT>
__device__ __forceinline__ void fc_tanh(const float* __restrict__ Wg,
                                        const float* __restrict__ bg,
                                        const float* __restrict__ p,
                                        float* __restrict__ dst, int tid)
{
    if (tid < OUT) {
        float a[8];
        #pragma unroll
        for (int u = 0; u < 8; ++u) a[u] = 0.f;
        #pragma unroll 4
        for (int i0 = 0; i0 < 1296; i0 += 8) {
            const float4 p0 = *(const float4*)&p[i0];
            const float4 p1 = *(const float4*)&p[i0+4];
            a[0] = fmaf(p0.x, Wg[(i0+0)*OUT + tid], a[0]);
            a[1] = fmaf(p0.y, Wg[(i0+1)*OUT + tid], a[1]);
            a[2] = fmaf(p0.z, Wg[(i0+2)*OUT + tid], a[2]);
            a[3] = fmaf(p0.w, Wg[(i0+3)*OUT + tid], a[3]);
            a[4] = fmaf(p1.x, Wg[(i0+4)*OUT + tid], a[4]);
            a[5] = fmaf(p1.y, Wg[(i0+5)*OUT + tid], a[5]);
            a[6] = fmaf(p1.z, Wg[(i0+6)*OUT + tid], a[6]);
            a[7] = fmaf(p1.w, Wg[(i0+7)*OUT + tid], a[7]);
        }
        float s = ((a[0]+a[1])+(a[2]+a[3])) + ((a[4]+a[5])+(a[6]+a[7])) + bg[tid];
        dst[tid] = tanhf(s);
    }
}

__device__ __forceinline__ void trunk_pass(SharedBufs& sb, int tid,
                                           const float* __restrict__ w1g,
                                           const float* __restrict__ b1g,
                                           const float* __restrict__ w2g,
                                           const float* __restrict__ b2g)
{
    // ---- conv1 5x5 pad2 + relu -> h1p. thread = (y, c): c=tid&7 so a y-group
    // of 8 lanes broadcasts the same rp40 row. Reads the -1-padded rp40 with
    // exact algebraic pad correction folded into acc init (validated r5-r8).
    if (tid < 224) {
        const int c = tid & 7;
        const int y = tid >> 3;
        float wreg[25];
        #pragma unroll
        for (int t = 0; t < 25; ++t) wreg[t] = w1g[c*25 + t];
        float csR[5];
        float S_all = 0.f, SR = 0.f;
        #pragma unroll
        for (int kx = 0; kx < 5; ++kx) {
            float a = wreg[kx] + wreg[5+kx] + wreg[10+kx] + wreg[15+kx] + wreg[20+kx];
            float ex = 0.f;
            if (y == 0)       ex = wreg[kx] + wreg[5+kx];   // rows ky=0,1 oob
            else if (y == 1)  ex = wreg[kx];                // row ky=0 oob
            if (y == 26)      ex += wreg[20+kx];            // row ky=4 oob
            else if (y == 27) ex += wreg[15+kx] + wreg[20+kx];
            csR[kx] = a - ex;
            S_all += a; SR += csR[kx];
        }
        const float corrI = S_all - SR;       // rows-oob, all kx (0 for inner y)
        const float bias  = b1g[c];
        float acc[28];
        #pragma unroll
        for (int x = 0; x < 28; ++x) acc[x] = bias + corrI;
        acc[0]  += csR[0] + csR[1];           // cols kx=0,1 oob at x=0
        acc[1]  += csR[0];
        acc[26] += csR[4];
        acc[27] += csR[3] + csR[4];
        #pragma unroll
        for (int ky = 0; ky < 5; ++ky) {
            // rp40 rows y+4..y+8, cols 4..35 (state cols -2..29), 16B-aligned
            const float4* rr = (const float4*)&sb.rp40[(y+4+ky)*RP40S + 4];
            float rv[32];
            #pragma unroll
            for (int q = 0; q < 8; ++q) {
                float4 t = rr[q];
                rv[q*4+0]=t.x; rv[q*4+1]=t.y; rv[q*4+2]=t.z; rv[q*4+3]=t.w;
            }
            #pragma unroll
            for (int kx = 0; kx < 5; ++kx) {
                const float w = wreg[ky*5+kx];
                #pragma unroll
                for (int x = 0; x < 28; ++x) acc[x] = fmaf(w, rv[x+kx], acc[x]);
            }
        }
        // b64 stores: row base (c*28+y)*34+2 is even
        float2* hp = (float2*)&sb.h1p[(c*28 + y)*H1W + 2];
        #pragma unroll
        for (int x = 0; x < 14; ++x)
            hp[x] = make_float2(fmaxf(acc[2*x], 0.f), fmaxf(acc[2*x+1], 0.f));
    }
    __syncthreads();

    // ---- conv2 5x5 pad2 + relu + maxpool3 -> pbuf[1296].
    // c-PAIRED: 240 thr = cpair(8) x h(2) x pyg(5) x pxg(3); each thread
    // computes ONE pooled row (3 outputs) for TWO channels cA=2*cpair, cB=+1
    // from a single set of row loads (halves LDS pipe traffic). Rows read as
    // 7 x ds_read_b64 from even-floored col; pxg==1 shifts by 1 via cndmask.
    // w2/b2 from global (12.8 KB, L1-resident). acc 54 + wA/wB 50 + f 14
    // ~ 125 regs -> VGPR cap 168 (3 waves/SIMD = 12 waves/CU = 3 blocks x 4).
    if (tid < 240) {
        const int cpair = tid / 30;
        const int sp    = tid % 30;
        const int h     = sp / 15;
        const int rem   = sp % 15;
        const int pyg   = rem / 3;
        const int pxg   = rem % 3;
        const int py    = pyg*2 + h;
        if (py < 9) {
            const int cA = cpair*2, cB = cA + 1;
            const int colw = (pxg*9) & ~1;     // {0,8,18}
            const bool oddc = (pxg == 1);      // col0=9 -> shift by 1
            const int crow0 = py * 3;          // first conv row / padded h1 row
            float accA[27], accB[27];
            {
                const float bA = b2g[cA], bB = b2g[cB];
                #pragma unroll
                for (int i = 0; i < 27; ++i) { accA[i] = bA; accB[i] = bB; }
            }
            for (int ic = 0; ic < 8; ++ic) {
                float wA[25], wB[25];
                {
                    const float* sA = &w2g[(cA*8+ic)*25];
                    const float* sB = &w2g[(cB*8+ic)*25];
                    #pragma unroll
                    for (int t = 0; t < 25; ++t) { wA[t] = sA[t]; wB[t] = sB[t]; }
                }
                #pragma unroll
                for (int yy = 0; yy < 7; ++yy) {
                    const int rr = crow0 + yy;               // padded row 0..32
                    if ((unsigned)(rr - 2) > 27u) continue;  // pad row (zero)
                    const float2* h2 = (const float2*)&sb.h1p[(ic*28 + (rr-2))*H1W + colw];
                    float f[14];
                    #pragma unroll
                    for (int q = 0; q < 7; ++q) {
                        float2 t = h2[q];
                        f[2*q] = t.x; f[2*q+1] = t.y;
                    }
                    float rowv[13];
                    #pragma unroll
                    for (int j = 0; j < 13; ++j) rowv[j] = oddc ? f[j+1] : f[j];
                    #pragma unroll
                    for (int t = 0; t < 3; ++t) {
                        const int ky = yy - t;
                        if (ky < 0 || ky > 4) continue;      // static after unroll
                        #pragma unroll
                        for (int kx = 0; kx < 5; ++kx) {
                            const float wa = wA[ky*5+kx];
                            const float wb = wB[ky*5+kx];
                            #pragma unroll
                            for (int u = 0; u < 9; ++u) {
                                accA[t*9+u] = fmaf(wa, rowv[u+kx], accA[t*9+u]);
                                accB[t*9+u] = fmaf(wb, rowv[u+kx], accB[t*9+u]);
                            }
                        }
                    }
                }
            }
            #pragma unroll
            for (int pxi = 0; pxi < 3; ++pxi) {
                float mA = accA[pxi*3], mB = accB[pxi*3];
                #pragma unroll
                for (int dy = 0; dy < 3; ++dy)
                    #pragma unroll
                    for (int dx = 0; dx < 3; ++dx) {
                        mA = fmaxf(mA, accA[dy*9 + pxi*3 + dx]);
                        mB = fmaxf(mB, accB[dy*9 + pxi*3 + dx]);
                    }
                sb.pbuf[cA*81 + py*9 + pxg*3 + pxi] = fmaxf(mA, 0.f);
                sb.pbuf[cB*81 + py*9 + pxg*3 + pxi] = fmaxf(mB, 0.f);
            }
        }
    }
    __syncthreads();
}

__device__ __forceinline__ void depthwise13_regs(SharedBufs& sb, int y, int x0,
                                                 float& a0, float& a1,
                                                 float& a2, float& a3)
{
    // out(y,x) = sum_{ky,kx} wker[ky*13+kx] * rp40[y+ky][x+kx]; results stay
    // in registers -- caller barriers, then writes rp40/o directly (no pbuf).
    a0=0.f; a1=0.f; a2=0.f; a3=0.f;
    #pragma unroll 1
    for (int ky = 0; ky < 13; ++ky) {
        const float4* rr = (const float4*)&sb.rp40[(y+ky)*RP40S + x0];
        float rv[16];
        #pragma unroll
        for (int q = 0; q < 4; ++q) {
            float4 t = rr[q];
            rv[q*4+0]=t.x; rv[q*4+1]=t.y; rv[q*4+2]=t.z; rv[q*4+3]=t.w;
        }
        const float* wr = &sb.wker[ky*13];
        #pragma unroll
        for (int kx = 0; kx < 13; ++kx) {
            const float w = wr[kx];
            a0 = fmaf(w, rv[kx+0], a0);
            a1 = fmaf(w, rv[kx+1], a1);
            a2 = fmaf(w, rv[kx+2], a2);
            a3 = fmaf(w, rv[kx+3], a3);
        }
    }
}

__global__ __launch_bounds__(256) __attribute__((amdgpu_num_vgpr(168)))
void modeld_fused(const float* __restrict__ x,
                  const float* __restrict__ n_w1, const float* __restrict__ n_b1,
                  const float* __restrict__ n_w2, const float* __restrict__ n_b2,
                  const float* __restrict__ n_wl, const float* __restrict__ n_bl,
                  const float* __restrict__ c_w1, const float* __restrict__ c_b1,
                  const float* __restrict__ c_w2, const float* __restrict__ c_b2,
                  const float* __restrict__ c_wl, const float* __restrict__ c_bl,
                  float* __restrict__ out,
                  int* __restrict__ counter, int B)
{
    __shared__ SharedBufs sb;
    const int tid = threadIdx.x;
    const int dy  = tid / 7;          // dw/state mapping: thread<196 owns
    const int dx0 = (tid % 7) * 4;    // outputs (dy, dx0..dx0+3)

    // one-time pad init: pads persist across samples (only interiors rewritten)
    for (int i = tid; i < 40*RP40S;   i += 256) sb.rp40[i] = -1.f;
    for (int i = tid; i < 8*28*H1W;   i += 256) sb.h1p[i]  = 0.f;

    while (true) {
        if (tid == 0) sb.next = atomicAdd(counter, 1);
        __syncthreads();                       // also orders pad init / prev sample
        const int b = sb.next;
        if (b >= B) break;                     // uniform exit

        // load x (float4 per dw mapping) into rp40 interior; keep in regs
        float cur[4] = {0.f, 0.f, 0.f, 0.f};
        if (tid < 196) {
            const float4 t = *(const float4*)&x[b*784 + dy*28 + dx0];
            cur[0]=t.x; cur[1]=t.y; cur[2]=t.z; cur[3]=t.w;
            float* rp = &sb.rp40[(dy+6)*RP40S + dx0 + 6];
            rp[0]=t.x; rp[1]=t.y; rp[2]=t.z; rp[3]=t.w;
        }
        __syncthreads();

        // ---- n-trunk -> num[0..9]
        trunk_pass(sb, tid, n_w1, n_b1, n_w2, n_b2);
        fc_tanh<10>(n_wl, n_bl, sb.pbuf, sb.num_s, tid);
        __syncthreads();

        float o[4];
        {
            const float n0 = sb.num_s[0];
            #pragma unroll
            for (int q = 0; q < 4; ++q) o[q] = n0 * cur[q];
        }

        // ---- 9 iterations
        for (int k = 1; k <= 9; ++k) {
            trunk_pass(sb, tid, c_w1, c_b1, c_w2, c_b2);       // rp40 -> pbuf[1296]
            fc_tanh<169>(c_wl, c_bl, sb.pbuf, sb.wker, tid);   // pbuf -> wker
            __syncthreads();
            float a0, a1, a2, a3;
            if (tid < 196) depthwise13_regs(sb, dy, dx0, a0, a1, a2, a3);
            __syncthreads();                   // all rp40 reads done before writes
            if (tid < 196) {
                const float nk = sb.num_s[k];
                o[0] = fmaf(nk, a0, o[0]);
                o[1] = fmaf(nk, a1, o[1]);
                o[2] = fmaf(nk, a2, o[2]);
                o[3] = fmaf(nk, a3, o[3]);
                float* rp = &sb.rp40[(dy+6)*RP40S + dx0 + 6];
                rp[0]=a0; rp[1]=a1; rp[2]=a2; rp[3]=a3;
            }
            __syncthreads();                   // new state visible to next conv1
        }

        if (tid < 196)
            *(float4*)&out[b*784 + dy*28 + dx0] = make_float4(o[0], o[1], o[2], o[3]);
        // no barrier needed: next iteration's grab+sync orders everything
    }
}

extern "C" void kernel_launch(void* const* d_in, const int* in_sizes, int n_in,
                              void* d_out, int out_size, void* d_ws, size_t ws_size,
                              hipStream_t stream)
{
    const float* x    = (const float*)d_in[0];
    const float* n_w1 = (const float*)d_in[1];
    const float* n_b1 = (const float*)d_in[2];
    const float* n_w2 = (const float*)d_in[3];
    const float* n_b2 = (const float*)d_in[4];
    const float* n_wl = (const float*)d_in[5];
    const float* n_bl = (const float*)d_in[6];
    const float* c_w1 = (const float*)d_in[7];
    const float* c_b1 = (const float*)d_in[8];
    const float* c_w2 = (const float*)d_in[9];
    const float* c_b2 = (const float*)d_in[10];
    const float* c_wl = (const float*)d_in[11];
    const float* c_bl = (const float*)d_in[12];
    float* out = (float*)d_out;

    const int B = in_sizes[0] / 784;
    hipMemsetAsync(d_ws, 0, sizeof(int), stream);   // work-stealing counter reset
    const int grid = B < 768 ? B : 768;             // 3 blocks/CU x 256 CUs
    hipLaunchKernelGGL(modeld_fused, dim3(grid), dim3(256), 0, stream,
                       x, n_w1, n_b1, n_w2, n_b2, n_wl, n_bl,
                       c_w1, c_b1, c_w2, c_b2, c_wl, c_bl, out,
                       (int*)d_ws, B);
}

// Round 10
// 1427.438 us; speedup vs baseline: 1.7604x; 1.7604x over previous
//
#include <hip/hip_runtime.h>
#include <math.h>

// Per-sample fully-fused iterated CNN. Persistent blocks, 256 threads, atomic
// work-stealing, 3 blocks/CU, FULL fp32 (rounds 3/4: any mantissa compression
// is chaotically amplified ~10x/iter -> fails). VGPR pinned by COUNT
// (amdgpu_num_vgpr; wave-based hints are broken: launch_bounds(256,3)->84,
// waves_per_eu(4)->64, both spilled catastrophically).
// LDS-PIPE diagnosis (r9): conv2's 1456 ds_read_b32/thread (H1W=31 odd ->
// scalar) ~530us of single-pipe time explains 3->4 blocks flat, prefetch
// flat, stagger flat. r9's c-PAIRING fix spilled (~190 live > 168 cap,
// WRITE_SIZE 225MB). THIS ROUND: register-neutral LDS cuts only --
// (1) H1W=34 (even) -> 7 x ds_read_b64 rows (vs 13 b32), odd-col pxg==1
//     shifted via per-lane cndmask (VALU is 4-SIMD-parallel; LDS pipe isn't);
// (2) conv1 stores float2 (14 vs 28 insts);
// (3) fc reads pbuf as float4 (324 vs 1296 insts).
// conv2 LDS insts/thread: 1456 -> 784 (2x wider each). No c-pairing.
// LDS 43408 -> 3 blocks/CU; VGPR cap 168 = 3 waves/SIMD (12 waves/CU) with
// scheduling slack (live set ~122).
#define RP40S 44   // (-1)-padded 40x44 state (16B-aligned rows)
#define H1W   34   // h1 col stride: EVEN (b64 rows); 2 left pads + 28 + 4
                   // right pads (zeros). pyg stride 204=12 mod 32, c-plane
                   // 952=24 mod 32 -> conv2 lane addrs spread across banks.

struct SharedBufs {
    float rp40[40*RP40S];   //  7040 B  (state, -1 pads, persists)
    float h1p[8*28*H1W];    // 30464 B  (conv1 activations, fp32, zero col-pads)
    float pbuf[1296];       //  5184 B  (pooled feats -> fc input, 16B-aligned)
    float wker[169];        //   676 B
    float num_s[10];        //    40 B
    int   next;             //     4 B  (work-stealing broadcast slot)
};                          // 43408 B -> 43520 block -> 3 blocks/CU

template<int OUT>
__device__ __forceinline__ void fc_tanh(const float* __restrict__ Wg,
                                        const float* __restrict__ bg,
                                        const float* __restrict__ p,
                                        float* __restrict__ dst, int tid)
{
    if (tid < OUT) {
        float a[8];
        #pragma unroll
        for (int u = 0; u < 8; ++u) a[u] = 0.f;
        #pragma unroll 4
        for (int i0 = 0; i0 < 1296; i0 += 8) {
            const float4 p0 = *(const float4*)&p[i0];
            const float4 p1 = *(const float4*)&p[i0+4];
            a[0] = fmaf(p0.x, Wg[(i0+0)*OUT + tid], a[0]);
            a[1] = fmaf(p0.y, Wg[(i0+1)*OUT + tid], a[1]);
            a[2] = fmaf(p0.z, Wg[(i0+2)*OUT + tid], a[2]);
            a[3] = fmaf(p0.w, Wg[(i0+3)*OUT + tid], a[3]);
            a[4] = fmaf(p1.x, Wg[(i0+4)*OUT + tid], a[4]);
            a[5] = fmaf(p1.y, Wg[(i0+5)*OUT + tid], a[5]);
            a[6] = fmaf(p1.z, Wg[(i0+6)*OUT + tid], a[6]);
            a[7] = fmaf(p1.w, Wg[(i0+7)*OUT + tid], a[7]);
        }
        float s = ((a[0]+a[1])+(a[2]+a[3])) + ((a[4]+a[5])+(a[6]+a[7])) + bg[tid];
        dst[tid] = tanhf(s);
    }
}

__device__ __forceinline__ void trunk_pass(SharedBufs& sb, int tid,
                                           const float* __restrict__ w1g,
                                           const float* __restrict__ b1g,
                                           const float* __restrict__ w2g,
                                           const float* __restrict__ b2g)
{
    // ---- conv1 5x5 pad2 + relu -> h1p. thread = (y, c): c=tid&7 so a y-group
    // of 8 lanes broadcasts the same rp40 row. Reads the -1-padded rp40 with
    // exact algebraic pad correction folded into acc init (validated r5-r9).
    if (tid < 224) {
        const int c = tid & 7;
        const int y = tid >> 3;
        float wreg[25];
        #pragma unroll
        for (int t = 0; t < 25; ++t) wreg[t] = w1g[c*25 + t];
        float csR[5];
        float S_all = 0.f, SR = 0.f;
        #pragma unroll
        for (int kx = 0; kx < 5; ++kx) {
            float a = wreg[kx] + wreg[5+kx] + wreg[10+kx] + wreg[15+kx] + wreg[20+kx];
            float ex = 0.f;
            if (y == 0)       ex = wreg[kx] + wreg[5+kx];   // rows ky=0,1 oob
            else if (y == 1)  ex = wreg[kx];                // row ky=0 oob
            if (y == 26)      ex += wreg[20+kx];            // row ky=4 oob
            else if (y == 27) ex += wreg[15+kx] + wreg[20+kx];
            csR[kx] = a - ex;
            S_all += a; SR += csR[kx];
        }
        const float corrI = S_all - SR;       // rows-oob, all kx (0 for inner y)
        const float bias  = b1g[c];
        float acc[28];
        #pragma unroll
        for (int x = 0; x < 28; ++x) acc[x] = bias + corrI;
        acc[0]  += csR[0] + csR[1];           // cols kx=0,1 oob at x=0
        acc[1]  += csR[0];
        acc[26] += csR[4];
        acc[27] += csR[3] + csR[4];
        #pragma unroll
        for (int ky = 0; ky < 5; ++ky) {
            // rp40 rows y+4..y+8, cols 4..35 (state cols -2..29), 16B-aligned
            const float4* rr = (const float4*)&sb.rp40[(y+4+ky)*RP40S + 4];
            float rv[32];
            #pragma unroll
            for (int q = 0; q < 8; ++q) {
                float4 t = rr[q];
                rv[q*4+0]=t.x; rv[q*4+1]=t.y; rv[q*4+2]=t.z; rv[q*4+3]=t.w;
            }
            #pragma unroll
            for (int kx = 0; kx < 5; ++kx) {
                const float w = wreg[ky*5+kx];
                #pragma unroll
                for (int x = 0; x < 28; ++x) acc[x] = fmaf(w, rv[x+kx], acc[x]);
            }
        }
        // b64 stores: row base (c*28+y)*34+2 is even
        float2* hp = (float2*)&sb.h1p[(c*28 + y)*H1W + 2];
        #pragma unroll
        for (int x = 0; x < 14; ++x)
            hp[x] = make_float2(fmaxf(acc[2*x], 0.f), fmaxf(acc[2*x+1], 0.f));
    }
    __syncthreads();

    // ---- conv2 5x5 pad2 + relu + maxpool3 -> pbuf[1296].
    // 240 threads cover 16c x 5pyg x 3pxg; 2 pooled rows sequentially
    // (acc[27], live ~122 regs incl f[14]). Rows read as 7 x ds_read_b64 from
    // even-floored col {0,8,18}; pxg==1 (col0=9) selects shifted lane view via
    // 13 cndmask (VALU, SIMD-parallel -- cheaper than 6 extra LDS-pipe ops).
    // w2/b2 from global (12.8 KB, L1-resident broadcast; 15 lanes share c).
    if (tid < 240) {
        const int c    = tid / 15;
        const int rem  = tid % 15;
        const int pyg  = rem / 3;
        const int pxg  = rem % 3;
        const int colw = (pxg*9) & ~1;     // {0,8,18}
        const bool oddc = (pxg == 1);      // col0=9 -> shift unpacked by 1
        const float bias = b2g[c];
        #pragma unroll 1
        for (int h = 0; h < 2; ++h) {
            const int py = pyg*2 + h;
            if (py >= 9) break;            // only pyg==4,h==1
            const int crow0 = py * 3;      // first conv row (=first padded h1 row)
            float acc[27];                 // acc[t*9+u]: conv rows t=0..2, cols u=0..8
            #pragma unroll
            for (int i = 0; i < 27; ++i) acc[i] = bias;
            for (int ic = 0; ic < 8; ++ic) {
                float wreg[25];
                const float* wsrc = &w2g[(c*8+ic)*25];
                #pragma unroll
                for (int t = 0; t < 25; ++t) wreg[t] = wsrc[t];
                #pragma unroll
                for (int yy = 0; yy < 7; ++yy) {
                    const int rr = crow0 + yy;               // padded row 0..32
                    if ((unsigned)(rr - 2) > 27u) continue;  // pad row (zero)
                    const float2* h2 = (const float2*)&sb.h1p[(ic*28 + (rr-2))*H1W + colw];
                    float f[14];
                    #pragma unroll
                    for (int q = 0; q < 7; ++q) {
                        float2 t = h2[q];
                        f[2*q] = t.x; f[2*q+1] = t.y;
                    }
                    float rowv[13];
                    #pragma unroll
                    for (int j = 0; j < 13; ++j) rowv[j] = oddc ? f[j+1] : f[j];
                    #pragma unroll
                    for (int t = 0; t < 3; ++t) {
                        const int ky = yy - t;
                        if (ky < 0 || ky > 4) continue;      // static after unroll
                        #pragma unroll
                        for (int kx = 0; kx < 5; ++kx) {
                            const float w = wreg[ky*5+kx];
                            #pragma unroll
                            for (int u = 0; u < 9; ++u)
                                acc[t*9+u] = fmaf(w, rowv[u+kx], acc[t*9+u]);
                        }
                    }
                }
            }
            #pragma unroll
            for (int pxi = 0; pxi < 3; ++pxi) {
                float m = acc[pxi*3];
                #pragma unroll
                for (int dy = 0; dy < 3; ++dy)
                    #pragma unroll
                    for (int dx = 0; dx < 3; ++dx)
                        m = fmaxf(m, acc[dy*9 + pxi*3 + dx]);
                sb.pbuf[c*81 + py*9 + pxg*3 + pxi] = fmaxf(m, 0.f);
            }
        }
    }
    __syncthreads();
}

__device__ __forceinline__ void depthwise13_regs(SharedBufs& sb, int y, int x0,
                                                 float& a0, float& a1,
                                                 float& a2, float& a3)
{
    // out(y,x) = sum_{ky,kx} wker[ky*13+kx] * rp40[y+ky][x+kx]; results stay
    // in registers -- caller barriers, then writes rp40/o directly (no pbuf).
    a0=0.f; a1=0.f; a2=0.f; a3=0.f;
    #pragma unroll 1
    for (int ky = 0; ky < 13; ++ky) {
        const float4* rr = (const float4*)&sb.rp40[(y+ky)*RP40S + x0];
        float rv[16];
        #pragma unroll
        for (int q = 0; q < 4; ++q) {
            float4 t = rr[q];
            rv[q*4+0]=t.x; rv[q*4+1]=t.y; rv[q*4+2]=t.z; rv[q*4+3]=t.w;
        }
        const float* wr = &sb.wker[ky*13];
        #pragma unroll
        for (int kx = 0; kx < 13; ++kx) {
            const float w = wr[kx];
            a0 = fmaf(w, rv[kx+0], a0);
            a1 = fmaf(w, rv[kx+1], a1);
            a2 = fmaf(w, rv[kx+2], a2);
            a3 = fmaf(w, rv[kx+3], a3);
        }
    }
}

__global__ __launch_bounds__(256) __attribute__((amdgpu_num_vgpr(168)))
void modeld_fused(const float* __restrict__ x,
                  const float* __restrict__ n_w1, const float* __restrict__ n_b1,
                  const float* __restrict__ n_w2, const float* __restrict__ n_b2,
                  const float* __restrict__ n_wl, const float* __restrict__ n_bl,
                  const float* __restrict__ c_w1, const float* __restrict__ c_b1,
                  const float* __restrict__ c_w2, const float* __restrict__ c_b2,
                  const float* __restrict__ c_wl, const float* __restrict__ c_bl,
                  float* __restrict__ out,
                  int* __restrict__ counter, int B)
{
    __shared__ SharedBufs sb;
    const int tid = threadIdx.x;
    const int dy  = tid / 7;          // dw/state mapping: thread<196 owns
    const int dx0 = (tid % 7) * 4;    // outputs (dy, dx0..dx0+3)

    // one-time pad init: pads persist across samples (only interiors rewritten)
    for (int i = tid; i < 40*RP40S;   i += 256) sb.rp40[i] = -1.f;
    for (int i = tid; i < 8*28*H1W;   i += 256) sb.h1p[i]  = 0.f;

    while (true) {
        if (tid == 0) sb.next = atomicAdd(counter, 1);
        __syncthreads();                       // also orders pad init / prev sample
        const int b = sb.next;
        if (b >= B) break;                     // uniform exit

        // load x (float4 per dw mapping) into rp40 interior; keep in regs
        float cur[4] = {0.f, 0.f, 0.f, 0.f};
        if (tid < 196) {
            const float4 t = *(const float4*)&x[b*784 + dy*28 + dx0];
            cur[0]=t.x; cur[1]=t.y; cur[2]=t.z; cur[3]=t.w;
            float* rp = &sb.rp40[(dy+6)*RP40S + dx0 + 6];
            rp[0]=t.x; rp[1]=t.y; rp[2]=t.z; rp[3]=t.w;
        }
        __syncthreads();

        // ---- n-trunk -> num[0..9]
        trunk_pass(sb, tid, n_w1, n_b1, n_w2, n_b2);
        fc_tanh<10>(n_wl, n_bl, sb.pbuf, sb.num_s, tid);
        __syncthreads();

        float o[4];
        {
            const float n0 = sb.num_s[0];
            #pragma unroll
            for (int q = 0; q < 4; ++q) o[q] = n0 * cur[q];
        }

        // ---- 9 iterations
        for (int k = 1; k <= 9; ++k) {
            trunk_pass(sb, tid, c_w1, c_b1, c_w2, c_b2);       // rp40 -> pbuf[1296]
            fc_tanh<169>(c_wl, c_bl, sb.pbuf, sb.wker, tid);   // pbuf -> wker
            __syncthreads();
            float a0, a1, a2, a3;
            if (tid < 196) depthwise13_regs(sb, dy, dx0, a0, a1, a2, a3);
            __syncthreads();                   // all rp40 reads done before writes
            if (tid < 196) {
                const float nk = sb.num_s[k];
                o[0] = fmaf(nk, a0, o[0]);
                o[1] = fmaf(nk, a1, o[1]);
                o[2] = fmaf(nk, a2, o[2]);
                o[3] = fmaf(nk, a3, o[3]);
                float* rp = &sb.rp40[(dy+6)*RP40S + dx0 + 6];
                rp[0]=a0; rp[1]=a1; rp[2]=a2; rp[3]=a3;
            }
            __syncthreads();                   // new state visible to next conv1
        }

        if (tid < 196)
            *(float4*)&out[b*784 + dy*28 + dx0] = make_float4(o[0], o[1], o[2], o[3]);
        // no barrier needed: next iteration's grab+sync orders everything
    }
}

extern "C" void kernel_launch(void* const* d_in, const int* in_sizes, int n_in,
                              void* d_out, int out_size, void* d_ws, size_t ws_size,
                              hipStream_t stream)
{
    const float* x    = (const float*)d_in[0];
    const float* n_w1 = (const float*)d_in[1];
    const float* n_b1 = (const float*)d_in[2];
    const float* n_w2 = (const float*)d_in[3];
    const float* n_b2 = (const float*)d_in[4];
    const float* n_wl = (const float*)d_in[5];
    const float* n_bl = (const float*)d_in[6];
    const float* c_w1 = (const float*)d_in[7];
    const float* c_b1 = (const float*)d_in[8];
    const float* c_w2 = (const float*)d_in[9];
    const float* c_b2 = (const float*)d_in[10];
    const float* c_wl = (const float*)d_in[11];
    const float* c_bl = (const float*)d_in[12];
    float* out = (float*)d_out;

    const int B = in_sizes[0] / 784;
    hipMemsetAsync(d_ws, 0, sizeof(int), stream);   // work-stealing counter reset
    const int grid = B < 768 ? B : 768;             // 3 blocks/CU x 256 CUs
    hipLaunchKernelGGL(modeld_fused, dim3(grid), dim3(256), 0, stream,
                       x, n_w1, n_b1, n_w2, n_b2, n_wl, n_bl,
                       c_w1, c_b1, c_w2, c_b2, c_wl, c_bl, out,
                       (int*)d_ws, B);
}

// Round 11
// 1335.358 us; speedup vs baseline: 1.8817x; 1.0690x over previous
//
#include <hip/hip_runtime.h>
#include <math.h>

// Per-sample fully-fused iterated CNN. Persistent blocks, 256 threads, atomic
// work-stealing, 3 blocks/CU, FULL fp32 (r3/r4: any mantissa compression is
// chaotically amplified ~7000x over 9 iterations -> fails threshold).
// VGPR pinned by COUNT (amdgpu_num_vgpr; wave-based hints broken: they
// deliver 2x the requested waves -> catastrophic spill, r1/r5).
// Falsified theories: occupancy 3->4 blocks flat (r6); in-wave latency +3%
// only (r7); phase-lock stagger flat (r8); LDS-inst-count cut negative (r10:
// compiler already merges scalar LDS reads into ds_read2_b32, and cndmask
// VALU cost exceeded LDS savings).
// This round, on the proven r7 base (1342us best): (1) rp40 DOUBLE-BUFFER --
// dw reads rp[cur], writes rp[cur^1]: WAR hazard gone, one of 5 barriers/iter
// removed; (2) fc: float4 pbuf reads + unroll 4 = 32 outstanding L2 loads in
// the narrowest phase (fc streams 876KB of c_wl per sample-iter from L2).
// NOTE: SQ_LDS_BANK_CONFLICT ~1.6-2e8 is benign wave64 2-way aliasing. Phantom.
#define RP40S 44   // (-1)-padded 40x44 state (16B-aligned rows)
#define H1W   31   // h1 col stride: 2 left pads + 28 + 1 right pad (zeros)

struct SharedBufs {
    float rp40[2][40*RP40S]; // 14080 B  (state, -1 pads, double-buffered)
    float h1p[8*28*H1W];     // 27776 B  (conv1 activations, fp32, zero col-pads)
    float pbuf[1296];        //  5184 B  (pooled feats -> fc input, 16B-aligned)
    float wker[169];         //   676 B
    float num_s[10];         //    40 B
    int   next;              //     4 B  (work-stealing broadcast slot)
};                           // 47760 B -> 48128 block -> 3 blocks/CU

template<int OUT>
__device__ __forceinline__ void fc_tanh(const float* __restrict__ Wg,
                                        const float* __restrict__ bg,
                                        const float* __restrict__ p,
                                        float* __restrict__ dst, int tid)
{
    if (tid < OUT) {
        float a[8];
        #pragma unroll
        for (int u = 0; u < 8; ++u) a[u] = 0.f;
        #pragma unroll 4
        for (int i0 = 0; i0 < 1296; i0 += 8) {
            const float4 p0 = *(const float4*)&p[i0];
            const float4 p1 = *(const float4*)&p[i0+4];
            a[0] = fmaf(p0.x, Wg[(i0+0)*OUT + tid], a[0]);
            a[1] = fmaf(p0.y, Wg[(i0+1)*OUT + tid], a[1]);
            a[2] = fmaf(p0.z, Wg[(i0+2)*OUT + tid], a[2]);
            a[3] = fmaf(p0.w, Wg[(i0+3)*OUT + tid], a[3]);
            a[4] = fmaf(p1.x, Wg[(i0+4)*OUT + tid], a[4]);
            a[5] = fmaf(p1.y, Wg[(i0+5)*OUT + tid], a[5]);
            a[6] = fmaf(p1.z, Wg[(i0+6)*OUT + tid], a[6]);
            a[7] = fmaf(p1.w, Wg[(i0+7)*OUT + tid], a[7]);
        }
        float s = ((a[0]+a[1])+(a[2]+a[3])) + ((a[4]+a[5])+(a[6]+a[7])) + bg[tid];
        dst[tid] = tanhf(s);
    }
}

// conv2 helpers (r7-proven): static-indexed row load (clamped) + FMA block.
#define C2_LOADROW(dst, YY) {                                                  \
    int rr_ = crow0 + (YY); rr_ = rr_ < 2 ? 2 : (rr_ > 29 ? 29 : rr_);         \
    const float* hp_ = plane + (rr_ - 2)*H1W;                                  \
    _Pragma("unroll") for (int j = 0; j < 13; ++j) dst[j] = hp_[j]; }

#define C2_FMAROW(src, YY)                                                     \
    if ((unsigned)(crow0 + (YY) - 2) <= 27u) {                                 \
      _Pragma("unroll") for (int t = 0; t < 3; ++t) {                          \
        const int ky_ = (YY) - t;                                              \
        if (ky_ >= 0 && ky_ <= 4) {                                            \
          _Pragma("unroll") for (int kx = 0; kx < 5; ++kx) {                   \
            const float w_ = wreg[ky_*5+kx];                                   \
            _Pragma("unroll") for (int u = 0; u < 9; ++u)                      \
              acc[t*9+u] = fmaf(w_, src[u+kx], acc[t*9+u]); } } } }

__device__ __forceinline__ void trunk_pass(SharedBufs& sb,
                                           const float* __restrict__ rpc,
                                           int tid,
                                           const float* __restrict__ w1g,
                                           const float* __restrict__ b1g,
                                           const float* __restrict__ w2g,
                                           const float* __restrict__ b2g)
{
    // ---- conv1 5x5 pad2 + relu -> h1p. thread = (y, c): c=tid&7 so a y-group
    // of 8 lanes broadcasts the same rpc row. Reads the -1-padded state with
    // exact algebraic pad correction folded into acc init (validated r5-r10).
    if (tid < 224) {
        const int c = tid & 7;
        const int y = tid >> 3;
        float wreg[25];
        #pragma unroll
        for (int t = 0; t < 25; ++t) wreg[t] = w1g[c*25 + t];
        float csR[5];
        float S_all = 0.f, SR = 0.f;
        #pragma unroll
        for (int kx = 0; kx < 5; ++kx) {
            float a = wreg[kx] + wreg[5+kx] + wreg[10+kx] + wreg[15+kx] + wreg[20+kx];
            float ex = 0.f;
            if (y == 0)       ex = wreg[kx] + wreg[5+kx];   // rows ky=0,1 oob
            else if (y == 1)  ex = wreg[kx];                // row ky=0 oob
            if (y == 26)      ex += wreg[20+kx];            // row ky=4 oob
            else if (y == 27) ex += wreg[15+kx] + wreg[20+kx];
            csR[kx] = a - ex;
            S_all += a; SR += csR[kx];
        }
        const float corrI = S_all - SR;       // rows-oob, all kx (0 for inner y)
        const float bias  = b1g[c];
        float acc[28];
        #pragma unroll
        for (int x = 0; x < 28; ++x) acc[x] = bias + corrI;
        acc[0]  += csR[0] + csR[1];           // cols kx=0,1 oob at x=0
        acc[1]  += csR[0];
        acc[26] += csR[4];
        acc[27] += csR[3] + csR[4];
        #pragma unroll
        for (int ky = 0; ky < 5; ++ky) {
            // state rows y+4..y+8, cols 4..35 (state cols -2..29), 16B-aligned
            const float4* rr = (const float4*)&rpc[(y+4+ky)*RP40S + 4];
            float rv[32];
            #pragma unroll
            for (int q = 0; q < 8; ++q) {
                float4 t = rr[q];
                rv[q*4+0]=t.x; rv[q*4+1]=t.y; rv[q*4+2]=t.z; rv[q*4+3]=t.w;
            }
            #pragma unroll
            for (int kx = 0; kx < 5; ++kx) {
                const float w = wreg[ky*5+kx];
                #pragma unroll
                for (int x = 0; x < 28; ++x) acc[x] = fmaf(w, rv[x+kx], acc[x]);
            }
        }
        float* hp = &sb.h1p[(c*28 + y)*H1W + 2];
        #pragma unroll
        for (int x = 0; x < 28; ++x) hp[x] = fmaxf(acc[x], 0.f);
    }
    __syncthreads();

    // ---- conv2 5x5 pad2 + relu + maxpool3 -> pbuf[1296].
    // 240 threads cover 16c x 5pyg x 3pxg; 2 pooled rows sequentially
    // (acc[27], live ~120 regs). ra/rb ping-pong row prefetch (r7).
    // w2/b2 from global (12.8 KB, L1-resident broadcast; 15 lanes share c).
    if (tid < 240) {
        const int c    = tid / 15;
        const int rem  = tid % 15;
        const int pyg  = rem / 3;
        const int pxg  = rem % 3;
        const int col0 = pxg * 9;   // first padded h1 col needed
        const float bias = b2g[c];
        #pragma unroll 1
        for (int h = 0; h < 2; ++h) {
            const int py = pyg*2 + h;
            if (py >= 9) break;            // only pyg==4,h==1
            const int crow0 = py * 3;      // first conv row (=first padded h1 row)
            float acc[27];                 // acc[t*9+u]: conv rows t=0..2, cols u=0..8
            #pragma unroll
            for (int i = 0; i < 27; ++i) acc[i] = bias;
            for (int ic = 0; ic < 8; ++ic) {
                float wreg[25];
                const float* wsrc = &w2g[(c*8+ic)*25];
                #pragma unroll
                for (int t = 0; t < 25; ++t) wreg[t] = wsrc[t];
                const float* plane = &sb.h1p[ic*28*H1W + col0];
                float ra[13], rb[13];
                C2_LOADROW(ra, 0)
                C2_LOADROW(rb, 1)  C2_FMAROW(ra, 0)
                C2_LOADROW(ra, 2)  C2_FMAROW(rb, 1)
                C2_LOADROW(rb, 3)  C2_FMAROW(ra, 2)
                C2_LOADROW(ra, 4)  C2_FMAROW(rb, 3)
                C2_LOADROW(rb, 5)  C2_FMAROW(ra, 4)
                C2_LOADROW(ra, 6)  C2_FMAROW(rb, 5)
                                   C2_FMAROW(ra, 6)
            }
            #pragma unroll
            for (int pxi = 0; pxi < 3; ++pxi) {
                float m = acc[pxi*3];
                #pragma unroll
                for (int dy = 0; dy < 3; ++dy)
                    #pragma unroll
                    for (int dx = 0; dx < 3; ++dx)
                        m = fmaxf(m, acc[dy*9 + pxi*3 + dx]);
                sb.pbuf[c*81 + py*9 + pxg*3 + pxi] = fmaxf(m, 0.f);
            }
        }
    }
    __syncthreads();
}

__device__ __forceinline__ void depthwise13_regs(SharedBufs& sb,
                                                 const float* __restrict__ rpc,
                                                 int y, int x0,
                                                 float& a0, float& a1,
                                                 float& a2, float& a3)
{
    // out(y,x) = sum_{ky,kx} wker[ky*13+kx] * rpc[y+ky][x+kx]; results stay
    // in registers; caller writes them into the OTHER state buffer (no WAR).
    a0=0.f; a1=0.f; a2=0.f; a3=0.f;
    #pragma unroll 1
    for (int ky = 0; ky < 13; ++ky) {
        const float4* rr = (const float4*)&rpc[(y+ky)*RP40S + x0];
        float rv[16];
        #pragma unroll
        for (int q = 0; q < 4; ++q) {
            float4 t = rr[q];
            rv[q*4+0]=t.x; rv[q*4+1]=t.y; rv[q*4+2]=t.z; rv[q*4+3]=t.w;
        }
        const float* wr = &sb.wker[ky*13];
        #pragma unroll
        for (int kx = 0; kx < 13; ++kx) {
            const float w = wr[kx];
            a0 = fmaf(w, rv[kx+0], a0);
            a1 = fmaf(w, rv[kx+1], a1);
            a2 = fmaf(w, rv[kx+2], a2);
            a3 = fmaf(w, rv[kx+3], a3);
        }
    }
}

__global__ __launch_bounds__(256) __attribute__((amdgpu_num_vgpr(168)))
void modeld_fused(const float* __restrict__ x,
                  const float* __restrict__ n_w1, const float* __restrict__ n_b1,
                  const float* __restrict__ n_w2, const float* __restrict__ n_b2,
                  const float* __restrict__ n_wl, const float* __restrict__ n_bl,
                  const float* __restrict__ c_w1, const float* __restrict__ c_b1,
                  const float* __restrict__ c_w2, const float* __restrict__ c_b2,
                  const float* __restrict__ c_wl, const float* __restrict__ c_bl,
                  float* __restrict__ out,
                  int* __restrict__ counter, int B)
{
    __shared__ SharedBufs sb;
    const int tid = threadIdx.x;
    const int dy  = tid / 7;          // dw/state mapping: thread<196 owns
    const int dx0 = (tid % 7) * 4;    // outputs (dy, dx0..dx0+3)

    // one-time pad init for BOTH state buffers (pads persist; only interiors
    // are rewritten) and h1p zero pads.
    for (int i = tid; i < 2*40*RP40S; i += 256) sb.rp40[0][i] = -1.f;
    for (int i = tid; i < 8*28*H1W;   i += 256) sb.h1p[i]  = 0.f;

    while (true) {
        if (tid == 0) sb.next = atomicAdd(counter, 1);
        __syncthreads();                       // also orders pad init / prev sample
        const int b = sb.next;
        if (b >= B) break;                     // uniform exit

        // load x (float4 per dw mapping) into state buf 0; keep in regs
        float cur[4] = {0.f, 0.f, 0.f, 0.f};
        if (tid < 196) {
            const float4 t = *(const float4*)&x[b*784 + dy*28 + dx0];
            cur[0]=t.x; cur[1]=t.y; cur[2]=t.z; cur[3]=t.w;
            float* rp = &sb.rp40[0][(dy+6)*RP40S + dx0 + 6];
            rp[0]=t.x; rp[1]=t.y; rp[2]=t.z; rp[3]=t.w;
        }
        __syncthreads();

        // ---- n-trunk -> num[0..9]
        trunk_pass(sb, sb.rp40[0], tid, n_w1, n_b1, n_w2, n_b2);
        fc_tanh<10>(n_wl, n_bl, sb.pbuf, sb.num_s, tid);
        __syncthreads();

        float o[4];
        {
            const float n0 = sb.num_s[0];
            #pragma unroll
            for (int q = 0; q < 4; ++q) o[q] = n0 * cur[q];
        }

        // ---- 9 iterations, state ping-pongs between rp40[0] and rp40[1]
        int curbuf = 0;
        for (int k = 1; k <= 9; ++k) {
            const float* rpc = sb.rp40[curbuf];
            float*       rpn = sb.rp40[curbuf ^ 1];
            trunk_pass(sb, rpc, tid, c_w1, c_b1, c_w2, c_b2);  // rpc -> pbuf[1296]
            fc_tanh<169>(c_wl, c_bl, sb.pbuf, sb.wker, tid);   // pbuf -> wker
            __syncthreads();
            if (tid < 196) {
                float a0, a1, a2, a3;
                depthwise13_regs(sb, rpc, dy, dx0, a0, a1, a2, a3);
                // write NEW state into the other buffer: no WAR hazard, no
                // extra barrier (dw reads rpc only; rpn is idle this iter)
                const float nk = sb.num_s[k];
                o[0] = fmaf(nk, a0, o[0]);
                o[1] = fmaf(nk, a1, o[1]);
                o[2] = fmaf(nk, a2, o[2]);
                o[3] = fmaf(nk, a3, o[3]);
                float* rp = &rpn[(dy+6)*RP40S + dx0 + 6];
                rp[0]=a0; rp[1]=a1; rp[2]=a2; rp[3]=a3;
            }
            __syncthreads();                   // new state visible to next conv1
            curbuf ^= 1;
        }

        if (tid < 196)
            *(float4*)&out[b*784 + dy*28 + dx0] = make_float4(o[0], o[1], o[2], o[3]);
        // no barrier needed: next iteration's grab+sync orders everything
    }
}

extern "C" void kernel_launch(void* const* d_in, const int* in_sizes, int n_in,
                              void* d_out, int out_size, void* d_ws, size_t ws_size,
                              hipStream_t stream)
{
    const float* x    = (const float*)d_in[0];
    const float* n_w1 = (const float*)d_in[1];
    const float* n_b1 = (const float*)d_in[2];
    const float* n_w2 = (const float*)d_in[3];
    const float* n_b2 = (const float*)d_in[4];
    const float* n_wl = (const float*)d_in[5];
    const float* n_bl = (const float*)d_in[6];
    const float* c_w1 = (const float*)d_in[7];
    const float* c_b1 = (const float*)d_in[8];
    const float* c_w2 = (const float*)d_in[9];
    const float* c_b2 = (const float*)d_in[10];
    const float* c_wl = (const float*)d_in[11];
    const float* c_bl = (const float*)d_in[12];
    float* out = (float*)d_out;

    const int B = in_sizes[0] / 784;
    hipMemsetAsync(d_ws, 0, sizeof(int), stream);   // work-stealing counter reset
    const int grid = B < 768 ? B : 768;             // 3 blocks/CU x 256 CUs
    hipLaunchKernelGGL(modeld_fused, dim3(grid), dim3(256), 0, stream,
                       x, n_w1, n_b1, n_w2, n_b2, n_wl, n_bl,
                       c_w1, c_b1, c_w2, c_b2, c_wl, c_bl, out,
                       (int*)d_ws, B);
}

// Round 12
// 1299.330 us; speedup vs baseline: 1.9339x; 1.0277x over previous
//
#include <hip/hip_runtime.h>
#include <math.h>

// Per-sample fully-fused iterated CNN. Persistent blocks, 256 threads, atomic
// work-stealing, 3 blocks/CU, FULL fp32 (r3/r4: any mantissa compression is
// chaotically amplified over 9 iterations -> fails threshold). VGPR pinned by
// COUNT (amdgpu_num_vgpr; wave-based hints deliver 2x the requested waves ->
// catastrophic spill, r1/r5).
// Falsified: occupancy 3->4 flat (r6); in-wave latency +3% (r7); stagger flat
// (r8); c-pairing spilled (r9); b64+cndmask negative (r10). r11 (+dbuf state,
// -1 barrier, fc float4): 1335us best.
// This round, additive micro-bundle on r11:
//  (1) wker padded 13x16 -> dw kernel reads are 4 x ds_read_b128/row
//      (52 vs 169 LDS insts/thread) on the single-per-CU LDS pipe;
//  (2) conv1 pad-correction hoisted to kernel start (constants per thread;
//      deletes ~45 VALU x 224thr x 10 passes);
//  (3) fc unroll 8 -> 64 outstanding L2 loads in the narrowest phase.
#define RP40S 44   // (-1)-padded 40x44 state (16B-aligned rows)
#define H1W   31   // h1 col stride: 2 left pads + 28 + 1 right pad (zeros)

struct SharedBufs {
    float rp40[2][40*RP40S]; // 14080 B  (state, -1 pads, double-buffered)
    float h1p[8*28*H1W];     // 27776 B  (conv1 activations, fp32, zero col-pads)
    float pbuf[1296];        //  5184 B  (pooled feats -> fc input, 16B-aligned)
    float wker[13*16];       //   832 B  (13x13 kernel, rows padded to 16)
    float num_s[10];         //    40 B
    int   next;              //     4 B  (work-stealing broadcast slot)
};                           // 47916 B -> 48128 block -> 3 blocks/CU

template<int OUT, bool PAD>
__device__ __forceinline__ void fc_tanh(const float* __restrict__ Wg,
                                        const float* __restrict__ bg,
                                        const float* __restrict__ p,
                                        float* __restrict__ dst, int tid)
{
    if (tid < OUT) {
        float a[8];
        #pragma unroll
        for (int u = 0; u < 8; ++u) a[u] = 0.f;
        #pragma unroll 8
        for (int i0 = 0; i0 < 1296; i0 += 8) {
            const float4 p0 = *(const float4*)&p[i0];
            const float4 p1 = *(const float4*)&p[i0+4];
            a[0] = fmaf(p0.x, Wg[(i0+0)*OUT + tid], a[0]);
            a[1] = fmaf(p0.y, Wg[(i0+1)*OUT + tid], a[1]);
            a[2] = fmaf(p0.z, Wg[(i0+2)*OUT + tid], a[2]);
            a[3] = fmaf(p0.w, Wg[(i0+3)*OUT + tid], a[3]);
            a[4] = fmaf(p1.x, Wg[(i0+4)*OUT + tid], a[4]);
            a[5] = fmaf(p1.y, Wg[(i0+5)*OUT + tid], a[5]);
            a[6] = fmaf(p1.z, Wg[(i0+6)*OUT + tid], a[6]);
            a[7] = fmaf(p1.w, Wg[(i0+7)*OUT + tid], a[7]);
        }
        float s = ((a[0]+a[1])+(a[2]+a[3])) + ((a[4]+a[5])+(a[6]+a[7])) + bg[tid];
        dst[PAD ? (tid/13)*16 + (tid%13) : tid] = tanhf(s);
    }
}

// conv1 pad-correction constants (per thread, per weight set): true conv =
// computed-on-(-1)-pads + sum_oob(w); decomposed into a base (bias + rows-oob
// term, all x) and 4 edge-column terms. Depends only on (c, y, weights) ->
// hoisted to kernel start (validated algebra r5-r11).
__device__ __forceinline__ void conv1_corr(const float* __restrict__ w1g,
                                           const float* __restrict__ b1g,
                                           int c, int y,
                                           float& base, float& e0, float& e1,
                                           float& e26, float& e27)
{
    float wreg[25];
    #pragma unroll
    for (int t = 0; t < 25; ++t) wreg[t] = w1g[c*25 + t];
    float csR[5];
    float S_all = 0.f, SR = 0.f;
    #pragma unroll
    for (int kx = 0; kx < 5; ++kx) {
        float a = wreg[kx] + wreg[5+kx] + wreg[10+kx] + wreg[15+kx] + wreg[20+kx];
        float ex = 0.f;
        if (y == 0)       ex = wreg[kx] + wreg[5+kx];   // rows ky=0,1 oob
        else if (y == 1)  ex = wreg[kx];                // row ky=0 oob
        if (y == 26)      ex += wreg[20+kx];            // row ky=4 oob
        else if (y == 27) ex += wreg[15+kx] + wreg[20+kx];
        csR[kx] = a - ex;
        S_all += a; SR += csR[kx];
    }
    base = b1g[c] + (S_all - SR);
    e0  = csR[0] + csR[1];
    e1  = csR[0];
    e26 = csR[4];
    e27 = csR[3] + csR[4];
}

// conv2 helpers (r7-proven): static-indexed row load (clamped) + FMA block.
#define C2_LOADROW(dst, YY) {                                                  \
    int rr_ = crow0 + (YY); rr_ = rr_ < 2 ? 2 : (rr_ > 29 ? 29 : rr_);         \
    const float* hp_ = plane + (rr_ - 2)*H1W;                                  \
    _Pragma("unroll") for (int j = 0; j < 13; ++j) dst[j] = hp_[j]; }

#define C2_FMAROW(src, YY)                                                     \
    if ((unsigned)(crow0 + (YY) - 2) <= 27u) {                                 \
      _Pragma("unroll") for (int t = 0; t < 3; ++t) {                          \
        const int ky_ = (YY) - t;                                              \
        if (ky_ >= 0 && ky_ <= 4) {                                            \
          _Pragma("unroll") for (int kx = 0; kx < 5; ++kx) {                   \
            const float w_ = wreg[ky_*5+kx];                                   \
            _Pragma("unroll") for (int u = 0; u < 9; ++u)                      \
              acc[t*9+u] = fmaf(w_, src[u+kx], acc[t*9+u]); } } } }

__device__ __forceinline__ void trunk_pass(SharedBufs& sb,
                                           const float* __restrict__ rpc,
                                           int tid,
                                           const float* __restrict__ w1g,
                                           const float* __restrict__ w2g,
                                           const float* __restrict__ b2g,
                                           float base, float e0, float e1,
                                           float e26, float e27)
{
    // ---- conv1 5x5 pad2 + relu -> h1p. thread = (y, c): c=tid&7 so a y-group
    // of 8 lanes broadcasts the same rpc row. Pad correction pre-hoisted.
    if (tid < 224) {
        const int c = tid & 7;
        const int y = tid >> 3;
        float wreg[25];
        #pragma unroll
        for (int t = 0; t < 25; ++t) wreg[t] = w1g[c*25 + t];
        float acc[28];
        #pragma unroll
        for (int x = 0; x < 28; ++x) acc[x] = base;
        acc[0]  += e0;
        acc[1]  += e1;
        acc[26] += e26;
        acc[27] += e27;
        #pragma unroll
        for (int ky = 0; ky < 5; ++ky) {
            // state rows y+4..y+8, cols 4..35 (state cols -2..29), 16B-aligned
            const float4* rr = (const float4*)&rpc[(y+4+ky)*RP40S + 4];
            float rv[32];
            #pragma unroll
            for (int q = 0; q < 8; ++q) {
                float4 t = rr[q];
                rv[q*4+0]=t.x; rv[q*4+1]=t.y; rv[q*4+2]=t.z; rv[q*4+3]=t.w;
            }
            #pragma unroll
            for (int kx = 0; kx < 5; ++kx) {
                const float w = wreg[ky*5+kx];
                #pragma unroll
                for (int x = 0; x < 28; ++x) acc[x] = fmaf(w, rv[x+kx], acc[x]);
            }
        }
        float* hp = &sb.h1p[(c*28 + y)*H1W + 2];
        #pragma unroll
        for (int x = 0; x < 28; ++x) hp[x] = fmaxf(acc[x], 0.f);
    }
    __syncthreads();

    // ---- conv2 5x5 pad2 + relu + maxpool3 -> pbuf[1296].
    // 240 threads cover 16c x 5pyg x 3pxg; 2 pooled rows sequentially
    // (acc[27], live ~120 regs). ra/rb ping-pong row prefetch (r7).
    // w2/b2 from global (12.8 KB, L1-resident broadcast; 15 lanes share c).
    if (tid < 240) {
        const int c    = tid / 15;
        const int rem  = tid % 15;
        const int pyg  = rem / 3;
        const int pxg  = rem % 3;
        const int col0 = pxg * 9;   // first padded h1 col needed
        const float bias = b2g[c];
        #pragma unroll 1
        for (int h = 0; h < 2; ++h) {
            const int py = pyg*2 + h;
            if (py >= 9) break;            // only pyg==4,h==1
            const int crow0 = py * 3;      // first conv row (=first padded h1 row)
            float acc[27];                 // acc[t*9+u]: conv rows t=0..2, cols u=0..8
            #pragma unroll
            for (int i = 0; i < 27; ++i) acc[i] = bias;
            for (int ic = 0; ic < 8; ++ic) {
                float wreg[25];
                const float* wsrc = &w2g[(c*8+ic)*25];
                #pragma unroll
                for (int t = 0; t < 25; ++t) wreg[t] = wsrc[t];
                const float* plane = &sb.h1p[ic*28*H1W + col0];
                float ra[13], rb[13];
                C2_LOADROW(ra, 0)
                C2_LOADROW(rb, 1)  C2_FMAROW(ra, 0)
                C2_LOADROW(ra, 2)  C2_FMAROW(rb, 1)
                C2_LOADROW(rb, 3)  C2_FMAROW(ra, 2)
                C2_LOADROW(ra, 4)  C2_FMAROW(rb, 3)
                C2_LOADROW(rb, 5)  C2_FMAROW(ra, 4)
                C2_LOADROW(ra, 6)  C2_FMAROW(rb, 5)
                                   C2_FMAROW(ra, 6)
            }
            #pragma unroll
            for (int pxi = 0; pxi < 3; ++pxi) {
                float m = acc[pxi*3];
                #pragma unroll
                for (int dy = 0; dy < 3; ++dy)
                    #pragma unroll
                    for (int dx = 0; dx < 3; ++dx)
                        m = fmaxf(m, acc[dy*9 + pxi*3 + dx]);
                sb.pbuf[c*81 + py*9 + pxg*3 + pxi] = fmaxf(m, 0.f);
            }
        }
    }
    __syncthreads();
}

__device__ __forceinline__ void depthwise13_regs(SharedBufs& sb,
                                                 const float* __restrict__ rpc,
                                                 int y, int x0,
                                                 float& a0, float& a1,
                                                 float& a2, float& a3)
{
    // out(y,x) = sum_{ky,kx} wker[ky][kx] * rpc[y+ky][x+kx]; results stay in
    // registers; caller writes them into the OTHER state buffer (no WAR).
    // wker rows padded to 16 -> 4 x ds_read_b128 per row (vs 13 scalar).
    a0=0.f; a1=0.f; a2=0.f; a3=0.f;
    #pragma unroll 1
    for (int ky = 0; ky < 13; ++ky) {
        const float4* rr = (const float4*)&rpc[(y+ky)*RP40S + x0];
        float rv[16];
        #pragma unroll
        for (int q = 0; q < 4; ++q) {
            float4 t = rr[q];
            rv[q*4+0]=t.x; rv[q*4+1]=t.y; rv[q*4+2]=t.z; rv[q*4+3]=t.w;
        }
        const float4* wq = (const float4*)&sb.wker[ky*16];
        float wv[16];
        #pragma unroll
        for (int q = 0; q < 4; ++q) {
            float4 t = wq[q];
            wv[q*4+0]=t.x; wv[q*4+1]=t.y; wv[q*4+2]=t.z; wv[q*4+3]=t.w;
        }
        #pragma unroll
        for (int kx = 0; kx < 13; ++kx) {
            const float w = wv[kx];
            a0 = fmaf(w, rv[kx+0], a0);
            a1 = fmaf(w, rv[kx+1], a1);
            a2 = fmaf(w, rv[kx+2], a2);
            a3 = fmaf(w, rv[kx+3], a3);
        }
    }
}

__global__ __launch_bounds__(256) __attribute__((amdgpu_num_vgpr(168)))
void modeld_fused(const float* __restrict__ x,
                  const float* __restrict__ n_w1, const float* __restrict__ n_b1,
                  const float* __restrict__ n_w2, const float* __restrict__ n_b2,
                  const float* __restrict__ n_wl, const float* __restrict__ n_bl,
                  const float* __restrict__ c_w1, const float* __restrict__ c_b1,
                  const float* __restrict__ c_w2, const float* __restrict__ c_b2,
                  const float* __restrict__ c_wl, const float* __restrict__ c_bl,
                  float* __restrict__ out,
                  int* __restrict__ counter, int B)
{
    __shared__ SharedBufs sb;
    const int tid = threadIdx.x;
    const int dy  = tid / 7;          // dw/state mapping: thread<196 owns
    const int dx0 = (tid % 7) * 4;    // outputs (dy, dx0..dx0+3)

    // hoisted conv1 pad-correction constants (weights fixed for whole kernel)
    float nb=0.f, ne0=0.f, ne1=0.f, ne26=0.f, ne27=0.f;
    float cb=0.f, ce0=0.f, ce1=0.f, ce26=0.f, ce27=0.f;
    if (tid < 224) {
        conv1_corr(n_w1, n_b1, tid & 7, tid >> 3, nb, ne0, ne1, ne26, ne27);
        conv1_corr(c_w1, c_b1, tid & 7, tid >> 3, cb, ce0, ce1, ce26, ce27);
    }

    // one-time pad init for BOTH state buffers (pads persist; only interiors
    // are rewritten) and h1p zero pads.
    for (int i = tid; i < 2*40*RP40S; i += 256) sb.rp40[0][i] = -1.f;
    for (int i = tid; i < 8*28*H1W;   i += 256) sb.h1p[i]  = 0.f;

    while (true) {
        if (tid == 0) sb.next = atomicAdd(counter, 1);
        __syncthreads();                       // also orders pad init / prev sample
        const int b = sb.next;
        if (b >= B) break;                     // uniform exit

        // load x (float4 per dw mapping) into state buf 0; keep in regs
        float cur[4] = {0.f, 0.f, 0.f, 0.f};
        if (tid < 196) {
            const float4 t = *(const float4*)&x[b*784 + dy*28 + dx0];
            cur[0]=t.x; cur[1]=t.y; cur[2]=t.z; cur[3]=t.w;
            float* rp = &sb.rp40[0][(dy+6)*RP40S + dx0 + 6];
            rp[0]=t.x; rp[1]=t.y; rp[2]=t.z; rp[3]=t.w;
        }
        __syncthreads();

        // ---- n-trunk -> num[0..9]
        trunk_pass(sb, sb.rp40[0], tid, n_w1, n_w2, n_b2, nb, ne0, ne1, ne26, ne27);
        fc_tanh<10, false>(n_wl, n_bl, sb.pbuf, sb.num_s, tid);
        __syncthreads();

        float o[4];
        {
            const float n0 = sb.num_s[0];
            #pragma unroll
            for (int q = 0; q < 4; ++q) o[q] = n0 * cur[q];
        }

        // ---- 9 iterations, state ping-pongs between rp40[0] and rp40[1]
        int curbuf = 0;
        for (int k = 1; k <= 9; ++k) {
            const float* rpc = sb.rp40[curbuf];
            float*       rpn = sb.rp40[curbuf ^ 1];
            trunk_pass(sb, rpc, tid, c_w1, c_w2, c_b2, cb, ce0, ce1, ce26, ce27);
            fc_tanh<169, true>(c_wl, c_bl, sb.pbuf, sb.wker, tid);  // padded rows
            __syncthreads();
            if (tid < 196) {
                float a0, a1, a2, a3;
                depthwise13_regs(sb, rpc, dy, dx0, a0, a1, a2, a3);
                // write NEW state into the other buffer: no WAR hazard, no
                // extra barrier (dw reads rpc only; rpn is idle this iter)
                const float nk = sb.num_s[k];
                o[0] = fmaf(nk, a0, o[0]);
                o[1] = fmaf(nk, a1, o[1]);
                o[2] = fmaf(nk, a2, o[2]);
                o[3] = fmaf(nk, a3, o[3]);
                float* rp = &rpn[(dy+6)*RP40S + dx0 + 6];
                rp[0]=a0; rp[1]=a1; rp[2]=a2; rp[3]=a3;
            }
            __syncthreads();                   // new state visible to next conv1
            curbuf ^= 1;
        }

        if (tid < 196)
            *(float4*)&out[b*784 + dy*28 + dx0] = make_float4(o[0], o[1], o[2], o[3]);
        // no barrier needed: next iteration's grab+sync orders everything
    }
}

extern "C" void kernel_launch(void* const* d_in, const int* in_sizes, int n_in,
                              void* d_out, int out_size, void* d_ws, size_t ws_size,
                              hipStream_t stream)
{
    const float* x    = (const float*)d_in[0];
    const float* n_w1 = (const float*)d_in[1];
    const float* n_b1 = (const float*)d_in[2];
    const float* n_w2 = (const float*)d_in[3];
    const float* n_b2 = (const float*)d_in[4];
    const float* n_wl = (const float*)d_in[5];
    const float* n_bl = (const float*)d_in[6];
    const float* c_w1 = (const float*)d_in[7];
    const float* c_b1 = (const float*)d_in[8];
    const float* c_w2 = (const float*)d_in[9];
    const float* c_b2 = (const float*)d_in[10];
    const float* c_wl = (const float*)d_in[11];
    const float* c_bl = (const float*)d_in[12];
    float* out = (float*)d_out;

    const int B = in_sizes[0] / 784;
    hipMemsetAsync(d_ws, 0, sizeof(int), stream);   // work-stealing counter reset
    const int grid = B < 768 ? B : 768;             // 3 blocks/CU x 256 CUs
    hipLaunchKernelGGL(modeld_fused, dim3(grid), dim3(256), 0, stream,
                       x, n_w1, n_b1, n_w2, n_b2, n_wl, n_bl,
                       c_w1, c_b1, c_w2, c_b2, c_wl, c_bl, out,
                       (int*)d_ws, B);
}